// Round 1
// baseline (4537.392 us; speedup 1.0000x reference)
//
#include <hip/hip_runtime.h>
#include <hip/hip_bf16.h>
#include <math.h>

// Problem constants (B=2, T=S=2048, D=3072, H=16, hd=192, d_c=1024)
#define BB 2
#define TT 2048
#define DD 3072
#define NH 16
#define HD 192
#define DC 1024

// ---------------------------------------------------------------------------
// Generic fp32 GEMM: C[M][N] = A[M][K] @ B  (+bias)
//  TRANSB=false: B is K x N row-major (NN)
//  TRANSB=true : B is N x K row-major (NT, i.e. C = A @ B^T)
// 128x128 tile, 256 threads, 8x8 per thread, K-step 16.
// ---------------------------------------------------------------------------
template <bool TRANSB, bool BIAS>
__global__ __launch_bounds__(256) void gemm_k(const float* __restrict__ A,
                                              const float* __restrict__ B,
                                              const float* __restrict__ bias,
                                              float* __restrict__ C,
                                              int M, int N, int K) {
  __shared__ float As[16][132];
  __shared__ float Bs[16][132];
  const int n0 = blockIdx.x * 128;
  const int m0 = blockIdx.y * 128;
  const int tid = threadIdx.x;
  const int tx = tid & 15;       // 0..15 -> n micro
  const int ty = tid >> 4;       // 0..15 -> m micro
  const int am = tid >> 1;       // 0..127
  const int ak8 = (tid & 1) * 8; // 0 or 8
  const int bk = tid >> 4;       // 0..15
  const int bn8 = (tid & 15) * 8;

  float acc[8][8];
#pragma unroll
  for (int i = 0; i < 8; ++i)
#pragma unroll
    for (int j = 0; j < 8; ++j) acc[i][j] = 0.f;

  for (int k0 = 0; k0 < K; k0 += 16) {
    __syncthreads();
    {
      const float* ap = &A[(size_t)(m0 + am) * K + k0 + ak8];
      float4 a0 = *(const float4*)ap;
      float4 a1 = *(const float4*)(ap + 4);
      As[ak8 + 0][am] = a0.x; As[ak8 + 1][am] = a0.y;
      As[ak8 + 2][am] = a0.z; As[ak8 + 3][am] = a0.w;
      As[ak8 + 4][am] = a1.x; As[ak8 + 5][am] = a1.y;
      As[ak8 + 6][am] = a1.z; As[ak8 + 7][am] = a1.w;
    }
    if (TRANSB) {
      const float* bp = &B[(size_t)(n0 + am) * K + k0 + ak8];
      float4 b0 = *(const float4*)bp;
      float4 b1 = *(const float4*)(bp + 4);
      Bs[ak8 + 0][am] = b0.x; Bs[ak8 + 1][am] = b0.y;
      Bs[ak8 + 2][am] = b0.z; Bs[ak8 + 3][am] = b0.w;
      Bs[ak8 + 4][am] = b1.x; Bs[ak8 + 5][am] = b1.y;
      Bs[ak8 + 6][am] = b1.z; Bs[ak8 + 7][am] = b1.w;
    } else {
      const float* bp = &B[(size_t)(k0 + bk) * N + n0 + bn8];
      *(float4*)(&Bs[bk][bn8]) = *(const float4*)bp;
      *(float4*)(&Bs[bk][bn8 + 4]) = *(const float4*)(bp + 4);
    }
    __syncthreads();
#pragma unroll
    for (int k = 0; k < 16; ++k) {
      float a[8], b[8];
      *(float4*)(a) = *(const float4*)(&As[k][ty * 8]);
      *(float4*)(a + 4) = *(const float4*)(&As[k][ty * 8 + 4]);
      *(float4*)(b) = *(const float4*)(&Bs[k][tx * 8]);
      *(float4*)(b + 4) = *(const float4*)(&Bs[k][tx * 8 + 4]);
#pragma unroll
      for (int i = 0; i < 8; ++i)
#pragma unroll
        for (int j = 0; j < 8; ++j) acc[i][j] += a[i] * b[j];
    }
  }

#pragma unroll
  for (int i = 0; i < 8; ++i) {
    size_t row = (size_t)(m0 + ty * 8 + i);
    float* cp = &C[row * N + n0 + tx * 8];
    float o[8];
#pragma unroll
    for (int j = 0; j < 8; ++j) {
      float v = acc[i][j];
      if (BIAS) v += bias[n0 + tx * 8 + j];
      o[j] = v;
    }
    *(float4*)(cp) = *(float4*)(o);
    *(float4*)(cp + 4) = *(float4*)(o + 4);
  }
}

// ---------------------------------------------------------------------------
// LayerNorm over d_c=1024 per row; block = 256 threads, one row per block.
// Exact two-pass (mean, then var of centered values) to match reference.
// ---------------------------------------------------------------------------
__global__ __launch_bounds__(256) void ln_k(const float* __restrict__ cpre,
                                            const float* __restrict__ g,
                                            const float* __restrict__ bta,
                                            float* __restrict__ out) {
  const int row = blockIdx.x;
  const int tid = threadIdx.x;
  __shared__ float red1[4];
  __shared__ float red2[4];

  float4 v = *(const float4*)(&cpre[(size_t)row * DC + tid * 4]);
  float s = v.x + v.y + v.z + v.w;
#pragma unroll
  for (int mk = 32; mk; mk >>= 1) s += __shfl_xor(s, mk, 64);
  if ((tid & 63) == 0) red1[tid >> 6] = s;
  __syncthreads();
  float mu = (red1[0] + red1[1] + red1[2] + red1[3]) * (1.f / DC);

  float dx = v.x - mu, dy = v.y - mu, dz = v.z - mu, dw = v.w - mu;
  float s2 = dx * dx + dy * dy + dz * dz + dw * dw;
#pragma unroll
  for (int mk = 32; mk; mk >>= 1) s2 += __shfl_xor(s2, mk, 64);
  if ((tid & 63) == 0) red2[tid >> 6] = s2;
  __syncthreads();
  float var = (red2[0] + red2[1] + red2[2] + red2[3]) * (1.f / DC);
  float rs = rsqrtf(var + 1e-5f);

  float4 gg = *(const float4*)(&g[tid * 4]);
  float4 bb = *(const float4*)(&bta[tid * 4]);
  float4 o;
  o.x = dx * rs * gg.x + bb.x;
  o.y = dy * rs * gg.y + bb.y;
  o.z = dz * rs * gg.z + bb.z;
  o.w = dw * rs * gg.w + bb.w;
  *(float4*)(&out[(size_t)row * DC + tid * 4]) = o;
}

// ---------------------------------------------------------------------------
// Fused causal attention, head_dim=192, fp32, online softmax.
// Block: 256 threads = 16 q-rows x 16 lanes; s-tiles of 32.
// q comes straight from x (reference reshapes x into heads), pre-scaled.
// ---------------------------------------------------------------------------
__global__ __launch_bounds__(256) void attn_k(const float* __restrict__ x,
                                              const float* __restrict__ kf,
                                              const float* __restrict__ vf,
                                              float* __restrict__ ctx) {
  const int t0 = blockIdx.x * 16;
  const int h = blockIdx.y;
  const int b = blockIdx.z;
  const int tid = threadIdx.x;
  const int r = tid >> 4;  // 0..15 q-row
  const int c = tid & 15;  // 0..15 s-col group

  __shared__ float qs[16][192];
  __shared__ float ks[32][196];
  __shared__ float vs[32][196];
  __shared__ float wt[16][32];

  const float qscale = 0.0721687836487032f;  // 1/sqrt(192)

  // load q tile (16 x 192), scaled
  for (int i = tid; i < 768; i += 256) {
    int row = i / 48, col4 = (i % 48) * 4;
    float4 v = *(const float4*)(
        &x[((size_t)(b * TT + t0 + row)) * DD + h * HD + col4]);
    v.x *= qscale; v.y *= qscale; v.z *= qscale; v.w *= qscale;
    *(float4*)(&qs[row][col4]) = v;
  }

  float m_run = -INFINITY, l_run = 0.f;
  float acc[12];
#pragma unroll
  for (int j = 0; j < 12; ++j) acc[j] = 0.f;

  const int st_max = (t0 + 15) >> 5;  // inclusive s-tile bound (causal)
  for (int st = 0; st <= st_max; ++st) {
    const int s0 = st * 32;
    __syncthreads();
    // load k,v tiles (32 x 192 each)
    for (int i = tid; i < 1536; i += 256) {
      int row = i / 48, col4 = (i % 48) * 4;
      size_t gofs = ((size_t)(b * TT + s0 + row)) * DD + h * HD + col4;
      *(float4*)(&ks[row][col4]) = *(const float4*)(&kf[gofs]);
      *(float4*)(&vs[row][col4]) = *(const float4*)(&vf[gofs]);
    }
    __syncthreads();

    // scores for cols c and c+16
    float sc0 = 0.f, sc1 = 0.f;
#pragma unroll
    for (int d4 = 0; d4 < 192; d4 += 4) {
      float4 q = *(const float4*)(&qs[r][d4]);
      float4 k0 = *(const float4*)(&ks[c][d4]);
      float4 k1 = *(const float4*)(&ks[c + 16][d4]);
      sc0 += q.x * k0.x + q.y * k0.y + q.z * k0.z + q.w * k0.w;
      sc1 += q.x * k1.x + q.y * k1.y + q.z * k1.z + q.w * k1.w;
    }
    const int t_g = t0 + r;
    if (s0 + c > t_g) sc0 = -INFINITY;
    if (s0 + c + 16 > t_g) sc1 = -INFINITY;

    float tmax = fmaxf(sc0, sc1);
#pragma unroll
    for (int mk = 8; mk; mk >>= 1) tmax = fmaxf(tmax, __shfl_xor(tmax, mk, 16));
    float m_new = fmaxf(m_run, tmax);
    float corr = __expf(m_run - m_new);  // exp(-inf)=0 on first tile
    float p0 = __expf(sc0 - m_new);
    float p1 = __expf(sc1 - m_new);
    float lsum = p0 + p1;
#pragma unroll
    for (int mk = 8; mk; mk >>= 1) lsum += __shfl_xor(lsum, mk, 16);
    l_run = l_run * corr + lsum;
    m_run = m_new;
#pragma unroll
    for (int j = 0; j < 12; ++j) acc[j] *= corr;
    wt[r][c] = p0;
    wt[r][c + 16] = p1;
    __syncthreads();

    // PV: each lane owns d-slice [c*12, c*12+12)
    for (int s = 0; s < 32; ++s) {
      float w = wt[r][s];
      const float* vp = &vs[s][c * 12];
      float4 v0 = *(const float4*)(vp);
      float4 v1 = *(const float4*)(vp + 4);
      float4 v2 = *(const float4*)(vp + 8);
      acc[0] += w * v0.x; acc[1] += w * v0.y; acc[2] += w * v0.z; acc[3] += w * v0.w;
      acc[4] += w * v1.x; acc[5] += w * v1.y; acc[6] += w * v1.z; acc[7] += w * v1.w;
      acc[8] += w * v2.x; acc[9] += w * v2.y; acc[10] += w * v2.z; acc[11] += w * v2.w;
    }
  }

  const float inv_l = 1.f / l_run;
  float* cp = &ctx[((size_t)(b * TT + t0 + r)) * DD + h * HD + c * 12];
  float o[12];
#pragma unroll
  for (int j = 0; j < 12; ++j) o[j] = acc[j] * inv_l;
  *(float4*)(cp) = *(float4*)(o);
  *(float4*)(cp + 4) = *(float4*)(o + 4);
  *(float4*)(cp + 8) = *(float4*)(o + 8);
}

// ---------------------------------------------------------------------------
extern "C" void kernel_launch(void* const* d_in, const int* in_sizes, int n_in,
                              void* d_out, int out_size, void* d_ws,
                              size_t ws_size, hipStream_t stream) {
  const float* x    = (const float*)d_in[0];
  const float* Wq   = (const float*)d_in[1];
  const float* Wkv  = (const float*)d_in[2];
  const float* Wuk  = (const float*)d_in[3];
  const float* Wuv  = (const float*)d_in[4];
  const float* Wout = (const float*)d_in[5];
  const float* bout = (const float*)d_in[6];
  const float* lng  = (const float*)d_in[7];
  const float* lnb  = (const float*)d_in[8];

  float* out = (float*)d_out;
  float* ckv = out + (size_t)BB * TT * DD;  // second tuple output

  float* ws = (float*)d_ws;
  float* Ak    = ws;                    // 3072*1024      = 3,145,728
  float* cpre  = Ak + 3145728;          // 4096*1024      = 4,194,304
  float* kfull = cpre + 4194304;        // 4096*3072      = 12,582,912
  float* vfull = kfull + 12582912;      // 4096*3072      = 12,582,912
  float* ctx   = vfull + 12582912;      // 4096*3072      = 12,582,912

  // 1. absorbed_k = W_query @ W_uk          (NN)  M=3072 N=1024 K=3072
  gemm_k<false, false><<<dim3(8, 24), 256, 0, stream>>>(Wq, Wuk, nullptr, Ak,
                                                        3072, 1024, 3072);
  // 2. c_pre = x @ W_kv^T                   (NT)  M=4096 N=1024 K=3072
  gemm_k<true, false><<<dim3(8, 32), 256, 0, stream>>>(x, Wkv, nullptr, cpre,
                                                       4096, 1024, 3072);
  // 3. c_kv = LayerNorm(c_pre)  -> second output region
  ln_k<<<4096, 256, 0, stream>>>(cpre, lng, lnb, ckv);
  // 4. k_full = c_kv @ absorbed_k^T         (NT)  M=4096 N=3072 K=1024
  gemm_k<true, false><<<dim3(24, 32), 256, 0, stream>>>(ckv, Ak, nullptr,
                                                        kfull, 4096, 3072, 1024);
  // 5. v_full = c_kv @ W_uv^T               (NT)  M=4096 N=3072 K=1024
  gemm_k<true, false><<<dim3(24, 32), 256, 0, stream>>>(ckv, Wuv, nullptr,
                                                        vfull, 4096, 3072, 1024);
  // 6. fused causal attention -> ctx
  attn_k<<<dim3(TT / 16, NH, BB), 256, 0, stream>>>(x, kfull, vfull, ctx);
  // 7. out = ctx @ W_out^T + b_out          (NT+bias) M=4096 N=3072 K=3072
  gemm_k<true, true><<<dim3(24, 32), 256, 0, stream>>>(ctx, Wout, bout, out,
                                                       4096, 3072, 3072);
}

// Round 2
// 640.179 us; speedup vs baseline: 7.0877x; 7.0877x over previous
//
#include <hip/hip_runtime.h>
#include <hip/hip_bf16.h>
#include <math.h>

// Problem constants (B=2, T=S=2048, D=3072, H=16, hd=192, d_c=1024)
#define BB 2
#define TT 2048
#define DD 3072
#define NH 16
#define HD 192
#define DC 1024

typedef __attribute__((ext_vector_type(8))) short bh8;    // 8 bf16 = 4 VGPR
typedef __attribute__((ext_vector_type(4))) float f32x4;  // MFMA accum
typedef unsigned int u32;

__device__ __forceinline__ short f2b(float f) {
  __hip_bfloat16 h = __float2bfloat16(f);  // RNE
  return *reinterpret_cast<short*>(&h);
}

// async global->LDS, 16B per lane; LDS dest = wave-uniform base + lane*16
__device__ __forceinline__ void gload16(const void* g, void* lds) {
  __builtin_amdgcn_global_load_lds(
      (const __attribute__((address_space(1))) u32*)g,
      (__attribute__((address_space(3))) u32*)lds, 16, 0, 0);
}

// ---------------------------------------------------------------------------
// fp32 -> bf16 cast, 8 elems/thread, exact grid cover
// ---------------------------------------------------------------------------
__global__ __launch_bounds__(256) void cast_f2b_k(const float* __restrict__ in,
                                                  short* __restrict__ out) {
  size_t i = ((size_t)blockIdx.x * 256 + threadIdx.x) * 8;
  float4 v0 = *(const float4*)&in[i];
  float4 v1 = *(const float4*)&in[i + 4];
  bh8 o;
  o[0] = f2b(v0.x); o[1] = f2b(v0.y); o[2] = f2b(v0.z); o[3] = f2b(v0.w);
  o[4] = f2b(v1.x); o[5] = f2b(v1.y); o[6] = f2b(v1.z); o[7] = f2b(v1.w);
  *(bh8*)&out[i] = o;
}

// ---------------------------------------------------------------------------
// fp32 [R][C] -> bf16 [C][R] cast-transpose (64x64 LDS tiles)
// ---------------------------------------------------------------------------
__global__ __launch_bounds__(256) void castT_f2b_k(const float* __restrict__ in,
                                                   short* __restrict__ out,
                                                   int R, int C) {
  __shared__ float t[64][65];
  const int cx = blockIdx.x * 64, ry = blockIdx.y * 64;
  const int tid = threadIdx.x, lx = tid & 15, ly = tid >> 4;
#pragma unroll
  for (int i = 0; i < 4; ++i) {
    int r = ly + i * 16;
    float4 v = *(const float4*)&in[(size_t)(ry + r) * C + cx + lx * 4];
    t[r][lx * 4 + 0] = v.x; t[r][lx * 4 + 1] = v.y;
    t[r][lx * 4 + 2] = v.z; t[r][lx * 4 + 3] = v.w;
  }
  __syncthreads();
#pragma unroll
  for (int i = 0; i < 4; ++i) {
    int c = ly + i * 16;  // original column = output row
    ushort4 v;
    v.x = (unsigned short)f2b(t[lx * 4 + 0][c]);
    v.y = (unsigned short)f2b(t[lx * 4 + 1][c]);
    v.z = (unsigned short)f2b(t[lx * 4 + 2][c]);
    v.w = (unsigned short)f2b(t[lx * 4 + 3][c]);
    *(ushort4*)&out[(size_t)(cx + c) * R + ry + lx * 4] = v;
  }
}

// ---------------------------------------------------------------------------
// bf16 [2048][3072] -> bf16 [3072][2048] per-batch transpose (z = batch)
// ---------------------------------------------------------------------------
__global__ __launch_bounds__(256) void transpose_b16_k(
    const unsigned short* __restrict__ in, unsigned short* __restrict__ out) {
  __shared__ unsigned short t[64][65];
  const unsigned short* ib = in + (size_t)blockIdx.z * TT * DD;
  unsigned short* ob = out + (size_t)blockIdx.z * DD * TT;
  const int cx = blockIdx.x * 64, ry = blockIdx.y * 64;
  const int tid = threadIdx.x, lx = tid & 15, ly = tid >> 4;
#pragma unroll
  for (int i = 0; i < 4; ++i) {
    int r = ly + i * 16;
    ushort4 v = *(const ushort4*)&ib[(size_t)(ry + r) * DD + cx + lx * 4];
    t[r][lx * 4 + 0] = v.x; t[r][lx * 4 + 1] = v.y;
    t[r][lx * 4 + 2] = v.z; t[r][lx * 4 + 3] = v.w;
  }
  __syncthreads();
#pragma unroll
  for (int i = 0; i < 4; ++i) {
    int c = ly + i * 16;
    ushort4 v;
    v.x = t[lx * 4 + 0][c]; v.y = t[lx * 4 + 1][c];
    v.z = t[lx * 4 + 2][c]; v.w = t[lx * 4 + 3][c];
    *(ushort4*)&ob[(size_t)(cx + c) * TT + ry + lx * 4] = v;
  }
}

// ---------------------------------------------------------------------------
// bf16 GEMM (m97 structure): C[M][N] = A[M][K] @ Bt[N][K]^T  (+bias)
// 128x128 tile, BK=32, 4 waves (2x2), 4x4 16x16x32 frags/wave.
// LDS linear with chunk-XOR swizzle (kc ^ ((row>>1)&3)) applied on the
// global SOURCE address (global_load_lds dest must be linear) and on reads.
// ---------------------------------------------------------------------------
template <bool OUTBF, bool BIAS>
__global__ __launch_bounds__(256) void gemm_bf16(
    const short* __restrict__ A, const short* __restrict__ Bt,
    const float* __restrict__ bias, void* __restrict__ Cout,
    int M, int N, int K) {
  __shared__ short As[4096];  // [128][32] bf16, swizzled chunks
  __shared__ short Bs[4096];
  const int tid = threadIdx.x;
  const int w = tid >> 6, l = tid & 63, lm = l & 15, lg = l >> 4;
  const int wr = w >> 1, wc = w & 1;
  const int m0 = blockIdx.y * 128, n0 = blockIdx.x * 128;

  f32x4 acc[4][4] = {};

  for (int k0 = 0; k0 < K; k0 += 32) {
    __syncthreads();
#pragma unroll
    for (int c = 0; c < 2; ++c) {
      int p = c * 256 + w * 64 + l;         // chunk index 0..511
      int row = p >> 2, kc = p & 3;
      int g = kc ^ ((row >> 1) & 3);        // swizzled source chunk
      gload16(&A[(size_t)(m0 + row) * K + k0 + g * 8],
              &As[(c * 256 + w * 64) * 8]);
      gload16(&Bt[(size_t)(n0 + row) * K + k0 + g * 8],
              &Bs[(c * 256 + w * 64) * 8]);
    }
    __syncthreads();

    bh8 a[4], b[4];
#pragma unroll
    for (int mi = 0; mi < 4; ++mi) {
      int r = wr * 64 + mi * 16 + lm;
      a[mi] = *(const bh8*)&As[r * 32 + ((lg ^ ((r >> 1) & 3)) << 3)];
    }
#pragma unroll
    for (int ni = 0; ni < 4; ++ni) {
      int r = wc * 64 + ni * 16 + lm;
      b[ni] = *(const bh8*)&Bs[r * 32 + ((lg ^ ((r >> 1) & 3)) << 3)];
    }
#pragma unroll
    for (int mi = 0; mi < 4; ++mi)
#pragma unroll
      for (int ni = 0; ni < 4; ++ni)
        acc[mi][ni] = __builtin_amdgcn_mfma_f32_16x16x32_bf16(
            a[mi], b[ni], acc[mi][ni], 0, 0, 0);
  }

  // epilogue: C layout col=lane&15, row=(lane>>4)*4+reg   [m89]
#pragma unroll
  for (int mi = 0; mi < 4; ++mi) {
#pragma unroll
    for (int ni = 0; ni < 4; ++ni) {
      int row = m0 + wr * 64 + mi * 16 + lg * 4;
      int col = n0 + wc * 64 + ni * 16 + lm;
      float bi = 0.f;
      if (BIAS) bi = bias[col];
#pragma unroll
      for (int r = 0; r < 4; ++r) {
        float v = acc[mi][ni][r] + bi;
        if (OUTBF)
          ((short*)Cout)[(size_t)(row + r) * N + col] = f2b(v);
        else
          ((float*)Cout)[(size_t)(row + r) * N + col] = v;
      }
    }
  }
}

// ---------------------------------------------------------------------------
// LayerNorm over d_c=1024 (fp32 in), writes fp32 (tuple output) + bf16 copy
// ---------------------------------------------------------------------------
__global__ __launch_bounds__(256) void ln_k(const float* __restrict__ cpre,
                                            const float* __restrict__ g,
                                            const float* __restrict__ bta,
                                            float* __restrict__ o32,
                                            short* __restrict__ o16) {
  const int row = blockIdx.x;
  const int tid = threadIdx.x;
  __shared__ float red1[4];
  __shared__ float red2[4];

  float4 v = *(const float4*)&cpre[(size_t)row * DC + tid * 4];
  float s = v.x + v.y + v.z + v.w;
#pragma unroll
  for (int mk = 32; mk; mk >>= 1) s += __shfl_xor(s, mk, 64);
  if ((tid & 63) == 0) red1[tid >> 6] = s;
  __syncthreads();
  float mu = (red1[0] + red1[1] + red1[2] + red1[3]) * (1.f / DC);

  float dx = v.x - mu, dy = v.y - mu, dz = v.z - mu, dw = v.w - mu;
  float s2 = dx * dx + dy * dy + dz * dz + dw * dw;
#pragma unroll
  for (int mk = 32; mk; mk >>= 1) s2 += __shfl_xor(s2, mk, 64);
  if ((tid & 63) == 0) red2[tid >> 6] = s2;
  __syncthreads();
  float var = (red2[0] + red2[1] + red2[2] + red2[3]) * (1.f / DC);
  float rs = rsqrtf(var + 1e-5f);

  float4 gg = *(const float4*)&g[tid * 4];
  float4 bb = *(const float4*)&bta[tid * 4];
  float4 o;
  o.x = dx * rs * gg.x + bb.x;
  o.y = dy * rs * gg.y + bb.y;
  o.z = dz * rs * gg.z + bb.z;
  o.w = dw * rs * gg.w + bb.w;
  *(float4*)&o32[(size_t)row * DC + tid * 4] = o;
  ushort4 ob;
  ob.x = (unsigned short)f2b(o.x); ob.y = (unsigned short)f2b(o.y);
  ob.z = (unsigned short)f2b(o.z); ob.w = (unsigned short)f2b(o.w);
  *(ushort4*)&o16[(size_t)row * DC + tid * 4] = ob;
}

// ---------------------------------------------------------------------------
// Flash attention, bf16 MFMA. Block = 4 waves x 32 q-rows = 128 q-rows.
// KVBLK=64. K staged [64][192] swizzled; V^T staged [192][64] swizzled
// (from pre-transposed global vT); P through per-wave swizzled LDS.
// ---------------------------------------------------------------------------
__global__ __launch_bounds__(256) void attn_mfma(
    const short* __restrict__ xb, const short* __restrict__ kfull,
    const short* __restrict__ vT, short* __restrict__ ctx) {
  __shared__ short Ks[64 * 192];   // 24 KB
  __shared__ short Vs[192 * 64];   // 24 KB  (V^T tile: [d][kv])
  __shared__ short Ps[4][32 * 64]; // 16 KB  (per-wave P, chunk-swizzled)

  const int b = blockIdx.z, h = blockIdx.y, q0 = blockIdx.x * 128;
  const int tid = threadIdx.x, w = tid >> 6, l = tid & 63;
  const int lm = l & 15, lg = l >> 4;
  const int qw0 = q0 + w * 32;
  const float QS = 0.07216878364870323f;  // 1/sqrt(192)

  // Q fragments resident: 2 rowgroups x 6 k-frags
  bh8 qf[2][6];
#pragma unroll
  for (int rg = 0; rg < 2; ++rg) {
    const short* qrow = &xb[(size_t)(b * TT + qw0 + rg * 16 + lm) * DD + h * HD];
#pragma unroll
    for (int kq = 0; kq < 6; ++kq)
      qf[rg][kq] = *(const bh8*)&qrow[kq * 32 + lg * 8];
  }

  f32x4 o[2][12] = {};
  float mrun[2][4], lrun[2][4];
#pragma unroll
  for (int rg = 0; rg < 2; ++rg)
#pragma unroll
    for (int r = 0; r < 4; ++r) { mrun[rg][r] = -INFINITY; lrun[rg][r] = 0.f; }

  const int ntiles = q0 / 64 + 2;  // causal: kv up to q0+127
  for (int st = 0; st < ntiles; ++st) {
    const int s0 = st * 64;
    __syncthreads();
    // stage K [64][192] and V^T [192][64], 6 x 16B/lane each
#pragma unroll
    for (int c = 0; c < 6; ++c) {
      int p = c * 256 + w * 64 + l;  // 0..1535
      {
        int krow = p / 24, kc = p - krow * 24;
        int g = kc ^ (krow & 7);
        gload16(&kfull[(size_t)(b * TT + s0 + krow) * DD + h * HD + g * 8],
                &Ks[(c * 256 + w * 64) * 8]);
      }
      {
        int vrow = p >> 3, kc = p & 7;
        int g = kc ^ (vrow & 7);
        gload16(&vT[(size_t)((b * NH + h) * HD + vrow) * TT + s0 + g * 8],
                &Vs[(c * 256 + w * 64) * 8]);
      }
    }
    __syncthreads();  // compiler drains vmcnt(0) here -> LDS ready

    // ---- QK^T: S[32][64] as 2rg x 4nf frags; K-frags reused across rg ----
    f32x4 s[2][4] = {};
#pragma unroll
    for (int nf = 0; nf < 4; ++nf) {
      const int krow = nf * 16 + lm;
      const short* kr = &Ks[krow * 192];
      bh8 kb[6];
#pragma unroll
      for (int kq = 0; kq < 6; ++kq)
        kb[kq] = *(const bh8*)&kr[(((kq * 4 + lg) ^ (krow & 7)) << 3)];
#pragma unroll
      for (int rg = 0; rg < 2; ++rg)
#pragma unroll
        for (int kq = 0; kq < 6; ++kq)
          s[rg][nf] = __builtin_amdgcn_mfma_f32_16x16x32_bf16(
              qf[rg][kq], kb[kq], s[rg][nf], 0, 0, 0);
    }

    // ---- online softmax (rows = (lane>>4)*4+r per rowgroup) ----
#pragma unroll
    for (int rg = 0; rg < 2; ++rg) {
      float pv[4][4];  // [nf][r]
#pragma unroll
      for (int nf = 0; nf < 4; ++nf)
#pragma unroll
        for (int r = 0; r < 4; ++r) {
          int col = s0 + nf * 16 + lm;
          int rowg = qw0 + rg * 16 + lg * 4 + r;
          pv[nf][r] = (col <= rowg) ? s[rg][nf][r] * QS : -INFINITY;
        }
#pragma unroll
      for (int r = 0; r < 4; ++r) {
        float mt = fmaxf(fmaxf(pv[0][r], pv[1][r]), fmaxf(pv[2][r], pv[3][r]));
#pragma unroll
        for (int mk = 1; mk < 16; mk <<= 1) mt = fmaxf(mt, __shfl_xor(mt, mk));
        float mnew = fmaxf(mrun[rg][r], mt);
        float corr = __expf(mrun[rg][r] - mnew);  // exp(-inf)=0 first tile
        mrun[rg][r] = mnew;
        float ls = 0.f;
#pragma unroll
        for (int nf = 0; nf < 4; ++nf) {
          float p = __expf(pv[nf][r] - mnew);
          pv[nf][r] = p;
          ls += p;
        }
#pragma unroll
        for (int mk = 1; mk < 16; mk <<= 1) ls += __shfl_xor(ls, mk);
        lrun[rg][r] = lrun[rg][r] * corr + ls;
#pragma unroll
        for (int nf = 0; nf < 12; ++nf) o[rg][nf][r] *= corr;
      }
      // write P (bf16) to per-wave LDS, chunk-XOR swizzled by row
#pragma unroll
      for (int nf = 0; nf < 4; ++nf)
#pragma unroll
        for (int r = 0; r < 4; ++r) {
          int prow = rg * 16 + lg * 4 + r;
          int col = nf * 16 + lm;
          int sc = (((col >> 3) ^ (prow & 7)) << 3) + (col & 7);
          Ps[w][prow * 64 + sc] = f2b(pv[nf][r]);
        }
    }

    // ---- PV: O[32][192] += P[32][64] @ V[64][192] (B = V^T tile) ----
    bh8 pa[2][2];
#pragma unroll
    for (int rg = 0; rg < 2; ++rg)
#pragma unroll
      for (int k2 = 0; k2 < 2; ++k2) {
        int prow = rg * 16 + lm;
        pa[rg][k2] =
            *(const bh8*)&Ps[w][prow * 64 + (((k2 * 4 + lg) ^ (prow & 7)) << 3)];
      }
#pragma unroll
    for (int nf = 0; nf < 12; ++nf) {
      int drow = nf * 16 + lm;
      const short* vr = &Vs[drow * 64];
      bh8 vb0 = *(const bh8*)&vr[((lg ^ (drow & 7)) << 3)];
      bh8 vb1 = *(const bh8*)&vr[(((4 + lg) ^ (drow & 7)) << 3)];
#pragma unroll
      for (int rg = 0; rg < 2; ++rg) {
        o[rg][nf] = __builtin_amdgcn_mfma_f32_16x16x32_bf16(pa[rg][0], vb0,
                                                            o[rg][nf], 0, 0, 0);
        o[rg][nf] = __builtin_amdgcn_mfma_f32_16x16x32_bf16(pa[rg][1], vb1,
                                                            o[rg][nf], 0, 0, 0);
      }
    }
  }

  // epilogue: ctx (bf16)
#pragma unroll
  for (int rg = 0; rg < 2; ++rg)
#pragma unroll
    for (int r = 0; r < 4; ++r) {
      float inv = 1.f / lrun[rg][r];
      int row = qw0 + rg * 16 + lg * 4 + r;
      short* cp = &ctx[(size_t)(b * TT + row) * DD + h * HD];
#pragma unroll
      for (int nf = 0; nf < 12; ++nf)
        cp[nf * 16 + lm] = f2b(o[rg][nf][r] * inv);
    }
}

// ---------------------------------------------------------------------------
extern "C" void kernel_launch(void* const* d_in, const int* in_sizes, int n_in,
                              void* d_out, int out_size, void* d_ws,
                              size_t ws_size, hipStream_t stream) {
  const float* x    = (const float*)d_in[0];
  const float* Wq   = (const float*)d_in[1];
  const float* Wkv  = (const float*)d_in[2];
  const float* Wuk  = (const float*)d_in[3];
  const float* Wuv  = (const float*)d_in[4];
  const float* Wout = (const float*)d_in[5];
  const float* bout = (const float*)d_in[6];
  const float* lng  = (const float*)d_in[7];
  const float* lnb  = (const float*)d_in[8];

  float* out   = (float*)d_out;
  float* ckv32 = out + (size_t)BB * TT * DD;  // second tuple output (fp32)

  // workspace layout (bytes; total 169,869,312 < round-1-proven 180 MB)
  char* W = (char*)d_ws;
  short* xb     = (short*)(W);                   // 25,165,824
  short* wbuf   = (short*)(W + 25165824);        // Wq_b then Wout_b: 18,874,368
  short* wukT   = (short*)(W + 44040192);        //  6,291,456
  short* wkvb   = (short*)(W + 50331648);        //  6,291,456
  short* wuvb   = (short*)(W + 56623104);        //  6,291,456
  short* akb    = (short*)(W + 62914560);        //  6,291,456
  float* cpre   = (float*)(W + 69206016);        // 16,777,216 (fp32)
  short* ckvb   = (short*)(W + 85983232);        //  8,388,608
  short* kfullb = (short*)(W + 94371840);        // 25,165,824
  short* vfullb = (short*)(W + 119537664);       // 25,165,824 (later = ctx)
  short* vTb    = (short*)(W + 144703488);       // 25,165,824
  short* ctxb   = vfullb;  // reuse: attn reads vT, writes ctx

  // casts
  cast_f2b_k<<<6144, 256, 0, stream>>>(x, xb);       // 12.58M
  cast_f2b_k<<<4608, 256, 0, stream>>>(Wq, wbuf);    //  9.44M
  cast_f2b_k<<<1536, 256, 0, stream>>>(Wkv, wkvb);
  cast_f2b_k<<<1536, 256, 0, stream>>>(Wuv, wuvb);
  castT_f2b_k<<<dim3(16, 48), 256, 0, stream>>>(Wuk, wukT, 3072, 1024);

  // 1. absorbed_k = Wq @ Wuk            M=3072 N=1024 K=3072 -> bf16
  gemm_bf16<true, false><<<dim3(8, 24), 256, 0, stream>>>(
      wbuf, wukT, nullptr, akb, 3072, 1024, 3072);
  // Wout cast reuses wbuf after GEMM1 (serial stream)
  cast_f2b_k<<<4608, 256, 0, stream>>>(Wout, wbuf);
  // 2. c_pre = x @ Wkv^T                M=4096 N=1024 K=3072 -> fp32
  gemm_bf16<false, false><<<dim3(8, 32), 256, 0, stream>>>(
      xb, wkvb, nullptr, cpre, 4096, 1024, 3072);
  // 3. LayerNorm -> ckv (fp32 output) + ckvb (bf16)
  ln_k<<<4096, 256, 0, stream>>>(cpre, lng, lnb, ckv32, ckvb);
  // 4. k_full = ckv @ absorbed_k^T      M=4096 N=3072 K=1024 -> bf16
  gemm_bf16<true, false><<<dim3(24, 32), 256, 0, stream>>>(
      ckvb, akb, nullptr, kfullb, 4096, 3072, 1024);
  // 5. v_full = ckv @ Wuv^T             M=4096 N=3072 K=1024 -> bf16
  gemm_bf16<true, false><<<dim3(24, 32), 256, 0, stream>>>(
      ckvb, wuvb, nullptr, vfullb, 4096, 3072, 1024);
  // 6. per-batch transpose v_full -> vT [b][hd][t]
  transpose_b16_k<<<dim3(48, 32, 2), 256, 0, stream>>>(
      (const unsigned short*)vfullb, (unsigned short*)vTb);
  // 7. flash attention -> ctx (bf16, overwrites vfull)
  attn_mfma<<<dim3(16, 16, 2), 256, 0, stream>>>(xb, kfullb, vTb, ctxb);
  // 8. out = ctx @ Wout^T + b_out       M=4096 N=3072 K=3072 -> fp32
  gemm_bf16<false, true><<<dim3(24, 32), 256, 0, stream>>>(
      ctxb, wbuf, bout, out, 4096, 3072, 3072);
}

// Round 3
// 479.624 us; speedup vs baseline: 9.4603x; 1.3348x over previous
//
#include <hip/hip_runtime.h>
#include <hip/hip_bf16.h>
#include <math.h>

// Problem constants (B=2, T=S=2048, D=3072, H=16, hd=192, d_c=1024)
#define BB 2
#define TT 2048
#define DD 3072
#define NH 16
#define HD 192
#define DC 1024

typedef __attribute__((ext_vector_type(8))) short bh8;    // 8 bf16 = 4 VGPR
typedef __attribute__((ext_vector_type(4))) float f32x4;  // MFMA accum
typedef unsigned int u32;

__device__ __forceinline__ short f2b(float f) {
  __hip_bfloat16 h = __float2bfloat16(f);  // RNE
  return *reinterpret_cast<short*>(&h);
}

// async global->LDS, 16B per lane; LDS dest = wave-uniform base + lane*16
__device__ __forceinline__ void gload16(const void* g, void* lds) {
  __builtin_amdgcn_global_load_lds(
      (const __attribute__((address_space(1))) u32*)g,
      (__attribute__((address_space(3))) u32*)lds, 16, 0, 0);
}

// ---------------------------------------------------------------------------
// fp32 -> bf16 cast, 8 elems/thread, exact grid cover
// ---------------------------------------------------------------------------
__global__ __launch_bounds__(256) void cast_f2b_k(const float* __restrict__ in,
                                                  short* __restrict__ out) {
  size_t i = ((size_t)blockIdx.x * 256 + threadIdx.x) * 8;
  float4 v0 = *(const float4*)&in[i];
  float4 v1 = *(const float4*)&in[i + 4];
  bh8 o;
  o[0] = f2b(v0.x); o[1] = f2b(v0.y); o[2] = f2b(v0.z); o[3] = f2b(v0.w);
  o[4] = f2b(v1.x); o[5] = f2b(v1.y); o[6] = f2b(v1.z); o[7] = f2b(v1.w);
  *(bh8*)&out[i] = o;
}

// ---------------------------------------------------------------------------
// fp32 [R][C] -> bf16 [C][R] cast-transpose (64x64 LDS tiles)
// ---------------------------------------------------------------------------
__global__ __launch_bounds__(256) void castT_f2b_k(const float* __restrict__ in,
                                                   short* __restrict__ out,
                                                   int R, int C) {
  __shared__ float t[64][65];
  const int cx = blockIdx.x * 64, ry = blockIdx.y * 64;
  const int tid = threadIdx.x, lx = tid & 15, ly = tid >> 4;
#pragma unroll
  for (int i = 0; i < 4; ++i) {
    int r = ly + i * 16;
    float4 v = *(const float4*)&in[(size_t)(ry + r) * C + cx + lx * 4];
    t[r][lx * 4 + 0] = v.x; t[r][lx * 4 + 1] = v.y;
    t[r][lx * 4 + 2] = v.z; t[r][lx * 4 + 3] = v.w;
  }
  __syncthreads();
#pragma unroll
  for (int i = 0; i < 4; ++i) {
    int c = ly + i * 16;  // original column = output row
    ushort4 v;
    v.x = (unsigned short)f2b(t[lx * 4 + 0][c]);
    v.y = (unsigned short)f2b(t[lx * 4 + 1][c]);
    v.z = (unsigned short)f2b(t[lx * 4 + 2][c]);
    v.w = (unsigned short)f2b(t[lx * 4 + 3][c]);
    *(ushort4*)&out[(size_t)(cx + c) * R + ry + lx * 4] = v;
  }
}

// ---------------------------------------------------------------------------
// bf16 [2048][3072] -> bf16 [3072][2048] per-batch transpose (z = batch)
// ---------------------------------------------------------------------------
__global__ __launch_bounds__(256) void transpose_b16_k(
    const unsigned short* __restrict__ in, unsigned short* __restrict__ out) {
  __shared__ unsigned short t[64][65];
  const unsigned short* ib = in + (size_t)blockIdx.z * TT * DD;
  unsigned short* ob = out + (size_t)blockIdx.z * DD * TT;
  const int cx = blockIdx.x * 64, ry = blockIdx.y * 64;
  const int tid = threadIdx.x, lx = tid & 15, ly = tid >> 4;
#pragma unroll
  for (int i = 0; i < 4; ++i) {
    int r = ly + i * 16;
    ushort4 v = *(const ushort4*)&ib[(size_t)(ry + r) * DD + cx + lx * 4];
    t[r][lx * 4 + 0] = v.x; t[r][lx * 4 + 1] = v.y;
    t[r][lx * 4 + 2] = v.z; t[r][lx * 4 + 3] = v.w;
  }
  __syncthreads();
#pragma unroll
  for (int i = 0; i < 4; ++i) {
    int c = ly + i * 16;
    ushort4 v;
    v.x = t[lx * 4 + 0][c]; v.y = t[lx * 4 + 1][c];
    v.z = t[lx * 4 + 2][c]; v.w = t[lx * 4 + 3][c];
    *(ushort4*)&ob[(size_t)(cx + c) * TT + ry + lx * 4] = v;
  }
}

// ---------------------------------------------------------------------------
// bf16 GEMM (m97 structure): C[M][N] = A[M][K] @ Bt[N][K]^T  (+bias)
// 128x128 tile, BK=32, 4 waves (2x2), 4x4 16x16x32 frags/wave.
// ---------------------------------------------------------------------------
template <bool OUTBF, bool BIAS>
__global__ __launch_bounds__(256) void gemm_bf16(
    const short* __restrict__ A, const short* __restrict__ Bt,
    const float* __restrict__ bias, void* __restrict__ Cout,
    int M, int N, int K) {
  __shared__ short As[4096];  // [128][32] bf16, swizzled chunks
  __shared__ short Bs[4096];
  const int tid = threadIdx.x;
  const int w = tid >> 6, l = tid & 63, lm = l & 15, lg = l >> 4;
  const int wr = w >> 1, wc = w & 1;
  const int m0 = blockIdx.y * 128, n0 = blockIdx.x * 128;

  f32x4 acc[4][4] = {};

  for (int k0 = 0; k0 < K; k0 += 32) {
    __syncthreads();
#pragma unroll
    for (int c = 0; c < 2; ++c) {
      int p = c * 256 + w * 64 + l;         // chunk index 0..511
      int row = p >> 2, kc = p & 3;
      int g = kc ^ ((row >> 1) & 3);        // swizzled source chunk
      gload16(&A[(size_t)(m0 + row) * K + k0 + g * 8],
              &As[(c * 256 + w * 64) * 8]);
      gload16(&Bt[(size_t)(n0 + row) * K + k0 + g * 8],
              &Bs[(c * 256 + w * 64) * 8]);
    }
    __syncthreads();

    bh8 a[4], b[4];
#pragma unroll
    for (int mi = 0; mi < 4; ++mi) {
      int r = wr * 64 + mi * 16 + lm;
      a[mi] = *(const bh8*)&As[r * 32 + ((lg ^ ((r >> 1) & 3)) << 3)];
    }
#pragma unroll
    for (int ni = 0; ni < 4; ++ni) {
      int r = wc * 64 + ni * 16 + lm;
      b[ni] = *(const bh8*)&Bs[r * 32 + ((lg ^ ((r >> 1) & 3)) << 3)];
    }
#pragma unroll
    for (int mi = 0; mi < 4; ++mi)
#pragma unroll
      for (int ni = 0; ni < 4; ++ni)
        acc[mi][ni] = __builtin_amdgcn_mfma_f32_16x16x32_bf16(
            a[mi], b[ni], acc[mi][ni], 0, 0, 0);
  }

  // epilogue: C layout col=lane&15, row=(lane>>4)*4+reg   [m89]
#pragma unroll
  for (int mi = 0; mi < 4; ++mi) {
#pragma unroll
    for (int ni = 0; ni < 4; ++ni) {
      int row = m0 + wr * 64 + mi * 16 + lg * 4;
      int col = n0 + wc * 64 + ni * 16 + lm;
      float bi = 0.f;
      if (BIAS) bi = bias[col];
#pragma unroll
      for (int r = 0; r < 4; ++r) {
        float v = acc[mi][ni][r] + bi;
        if (OUTBF)
          ((short*)Cout)[(size_t)(row + r) * N + col] = f2b(v);
        else
          ((float*)Cout)[(size_t)(row + r) * N + col] = v;
      }
    }
  }
}

// ---------------------------------------------------------------------------
// LayerNorm over d_c=1024 (fp32 in), writes fp32 (tuple output) + bf16 copy
// ---------------------------------------------------------------------------
__global__ __launch_bounds__(256) void ln_k(const float* __restrict__ cpre,
                                            const float* __restrict__ g,
                                            const float* __restrict__ bta,
                                            float* __restrict__ o32,
                                            short* __restrict__ o16) {
  const int row = blockIdx.x;
  const int tid = threadIdx.x;
  __shared__ float red1[4];
  __shared__ float red2[4];

  float4 v = *(const float4*)&cpre[(size_t)row * DC + tid * 4];
  float s = v.x + v.y + v.z + v.w;
#pragma unroll
  for (int mk = 32; mk; mk >>= 1) s += __shfl_xor(s, mk, 64);
  if ((tid & 63) == 0) red1[tid >> 6] = s;
  __syncthreads();
  float mu = (red1[0] + red1[1] + red1[2] + red1[3]) * (1.f / DC);

  float dx = v.x - mu, dy = v.y - mu, dz = v.z - mu, dw = v.w - mu;
  float s2 = dx * dx + dy * dy + dz * dz + dw * dw;
#pragma unroll
  for (int mk = 32; mk; mk >>= 1) s2 += __shfl_xor(s2, mk, 64);
  if ((tid & 63) == 0) red2[tid >> 6] = s2;
  __syncthreads();
  float var = (red2[0] + red2[1] + red2[2] + red2[3]) * (1.f / DC);
  float rs = rsqrtf(var + 1e-5f);

  float4 gg = *(const float4*)&g[tid * 4];
  float4 bb = *(const float4*)&bta[tid * 4];
  float4 o;
  o.x = dx * rs * gg.x + bb.x;
  o.y = dy * rs * gg.y + bb.y;
  o.z = dz * rs * gg.z + bb.z;
  o.w = dw * rs * gg.w + bb.w;
  *(float4*)&o32[(size_t)row * DC + tid * 4] = o;
  ushort4 ob;
  ob.x = (unsigned short)f2b(o.x); ob.y = (unsigned short)f2b(o.y);
  ob.z = (unsigned short)f2b(o.z); ob.w = (unsigned short)f2b(o.w);
  *(ushort4*)&o16[(size_t)row * DC + tid * 4] = ob;
}

// ---------------------------------------------------------------------------
// Flash attention, bf16 MFMA. Block = 4 waves; each wave owns 16 q-rows
// (QBLK=64). KVBLK=64. Flat LPT grid: heavy (high-qt) blocks first.
// K staged [64][192] chunk-swizzled; V^T staged [192][64] swizzled;
// P per-wave LDS (no barrier needed: same-wave write->read).
// ---------------------------------------------------------------------------
__global__ __launch_bounds__(256) void attn_mfma(
    const short* __restrict__ xb, const short* __restrict__ kfull,
    const short* __restrict__ vT, short* __restrict__ ctx) {
  __shared__ short Ks[64 * 192];   // 24 KB
  __shared__ short Vs[192 * 64];   // 24 KB  (V^T tile: [d][kv])
  __shared__ short Ps[4][16 * 64]; //  8 KB  (per-wave P, chunk-swizzled)

  const int idx = blockIdx.x;
  const int qt = 31 - (idx >> 5);  // q-tile, heavy first (LPT)
  const int bh = idx & 31;
  const int h = bh & 15, b = bh >> 4;
  const int tid = threadIdx.x, w = tid >> 6, l = tid & 63;
  const int lm = l & 15, lg = l >> 4;
  const int qw0 = qt * 64 + w * 16;  // wave's q-row base
  const float QS = 0.07216878364870323f;  // 1/sqrt(192)

  // Q fragments resident: rows qw0+lm, 6 k-frags
  bh8 qf[6];
  {
    const short* qrow = &xb[(size_t)(b * TT + qw0 + lm) * DD + h * HD];
#pragma unroll
    for (int kq = 0; kq < 6; ++kq)
      qf[kq] = *(const bh8*)&qrow[kq * 32 + lg * 8];
  }

  f32x4 o[12] = {};
  float mrun[4], lrun[4];
#pragma unroll
  for (int r = 0; r < 4; ++r) { mrun[r] = -INFINITY; lrun[r] = 0.f; }

  for (int st = 0; st <= qt; ++st) {
    const int s0 = st * 64;
    __syncthreads();
    // stage K [64][192] and V^T [192][64], 6 x 16B/lane each
#pragma unroll
    for (int c = 0; c < 6; ++c) {
      int p = c * 256 + w * 64 + l;  // 0..1535
      {
        int krow = p / 24, kc = p - krow * 24;
        int g = kc ^ (krow & 7);
        gload16(&kfull[(size_t)(b * TT + s0 + krow) * DD + h * HD + g * 8],
                &Ks[(c * 256 + w * 64) * 8]);
      }
      {
        int vrow = p >> 3, vc = p & 7;
        int gv = vc ^ (vrow & 7);
        gload16(&vT[(size_t)((b * NH + h) * HD + vrow) * TT + s0 + gv * 8],
                &Vs[(c * 256 + w * 64) * 8]);
      }
    }
    __syncthreads();  // compiler drains vmcnt(0) -> LDS ready

    // ---- QK^T: S[16 q][64 kv] as 4 nf frags ----
    f32x4 s[4] = {};
    __builtin_amdgcn_s_setprio(1);
#pragma unroll
    for (int nf = 0; nf < 4; ++nf) {
      const int krow = nf * 16 + lm;
      const short* kr = &Ks[krow * 192];
#pragma unroll
      for (int kq = 0; kq < 6; ++kq) {
        bh8 kb = *(const bh8*)&kr[(((kq * 4 + lg) ^ (krow & 7)) << 3)];
        s[nf] = __builtin_amdgcn_mfma_f32_16x16x32_bf16(qf[kq], kb, s[nf],
                                                        0, 0, 0);
      }
    }
    __builtin_amdgcn_s_setprio(0);

    // ---- online softmax (row = lg*4+r) ----
    float pv[4][4];  // [nf][r]
#pragma unroll
    for (int nf = 0; nf < 4; ++nf)
#pragma unroll
      for (int r = 0; r < 4; ++r) pv[nf][r] = s[nf][r] * QS;
    if (st == qt) {  // diagonal tile: apply causal mask (wave-uniform branch)
#pragma unroll
      for (int nf = 0; nf < 4; ++nf)
#pragma unroll
        for (int r = 0; r < 4; ++r)
          if (nf * 16 + lm > w * 16 + lg * 4 + r) pv[nf][r] = -INFINITY;
    }
#pragma unroll
    for (int r = 0; r < 4; ++r) {
      float mt = fmaxf(fmaxf(pv[0][r], pv[1][r]), fmaxf(pv[2][r], pv[3][r]));
#pragma unroll
      for (int mk = 1; mk < 16; mk <<= 1) mt = fmaxf(mt, __shfl_xor(mt, mk));
      float mnew = fmaxf(mrun[r], mt);
      float corr = __expf(mrun[r] - mnew);  // exp(-inf)=0 first tile
      mrun[r] = mnew;
      float ls = 0.f;
#pragma unroll
      for (int nf = 0; nf < 4; ++nf) {
        float p = __expf(pv[nf][r] - mnew);
        pv[nf][r] = p;
        ls += p;
      }
#pragma unroll
      for (int mk = 1; mk < 16; mk <<= 1) ls += __shfl_xor(ls, mk);
      lrun[r] = lrun[r] * corr + ls;
#pragma unroll
      for (int nf = 0; nf < 12; ++nf) o[nf][r] *= corr;
    }
    // write P (bf16) to per-wave LDS, chunk-XOR swizzled by row
#pragma unroll
    for (int nf = 0; nf < 4; ++nf)
#pragma unroll
      for (int r = 0; r < 4; ++r) {
        int prow = lg * 4 + r;
        int col = nf * 16 + lm;
        int sc = (((col >> 3) ^ (prow & 7)) << 3) + (col & 7);
        Ps[w][prow * 64 + sc] = f2b(pv[nf][r]);
      }
    // no barrier: Ps is same-wave write->read (lgkmcnt ordering)

    // ---- PV: O[16][192] += P[16][64] @ V[64][192] (B = V^T tile) ----
    bh8 pa0, pa1;
    {
      int prow = lm;
      pa0 = *(const bh8*)&Ps[w][prow * 64 + ((lg ^ (prow & 7)) << 3)];
      pa1 = *(const bh8*)&Ps[w][prow * 64 + (((4 + lg) ^ (prow & 7)) << 3)];
    }
    __builtin_amdgcn_s_setprio(1);
#pragma unroll
    for (int nf = 0; nf < 12; ++nf) {
      int drow = nf * 16 + lm;
      const short* vr = &Vs[drow * 64];
      bh8 vb0 = *(const bh8*)&vr[((lg ^ (drow & 7)) << 3)];
      bh8 vb1 = *(const bh8*)&vr[(((4 + lg) ^ (drow & 7)) << 3)];
      o[nf] = __builtin_amdgcn_mfma_f32_16x16x32_bf16(pa0, vb0, o[nf], 0, 0, 0);
      o[nf] = __builtin_amdgcn_mfma_f32_16x16x32_bf16(pa1, vb1, o[nf], 0, 0, 0);
    }
    __builtin_amdgcn_s_setprio(0);
  }

  // epilogue: ctx (bf16)
#pragma unroll
  for (int r = 0; r < 4; ++r) {
    float inv = 1.f / lrun[r];
    int row = qw0 + lg * 4 + r;
    short* cp = &ctx[(size_t)(b * TT + row) * DD + h * HD];
#pragma unroll
    for (int nf = 0; nf < 12; ++nf)
      cp[nf * 16 + lm] = f2b(o[nf][r] * inv);
  }
}

// ---------------------------------------------------------------------------
extern "C" void kernel_launch(void* const* d_in, const int* in_sizes, int n_in,
                              void* d_out, int out_size, void* d_ws,
                              size_t ws_size, hipStream_t stream) {
  const float* x    = (const float*)d_in[0];
  const float* Wq   = (const float*)d_in[1];
  const float* Wkv  = (const float*)d_in[2];
  const float* Wuk  = (const float*)d_in[3];
  const float* Wuv  = (const float*)d_in[4];
  const float* Wout = (const float*)d_in[5];
  const float* bout = (const float*)d_in[6];
  const float* lng  = (const float*)d_in[7];
  const float* lnb  = (const float*)d_in[8];

  float* out   = (float*)d_out;
  float* ckv32 = out + (size_t)BB * TT * DD;  // second tuple output (fp32)

  // workspace layout (bytes; total 169,869,312)
  char* W = (char*)d_ws;
  short* xb     = (short*)(W);                   // 25,165,824
  short* wbuf   = (short*)(W + 25165824);        // Wq_b then Wout_b
  short* wukT   = (short*)(W + 44040192);
  short* wkvb   = (short*)(W + 50331648);
  short* wuvb   = (short*)(W + 56623104);
  short* akb    = (short*)(W + 62914560);
  float* cpre   = (float*)(W + 69206016);        // fp32
  short* ckvb   = (short*)(W + 85983232);
  short* kfullb = (short*)(W + 94371840);
  short* vfullb = (short*)(W + 119537664);       // later = ctx
  short* vTb    = (short*)(W + 144703488);
  short* ctxb   = vfullb;  // reuse: attn reads vT, writes ctx

  // casts
  cast_f2b_k<<<6144, 256, 0, stream>>>(x, xb);
  cast_f2b_k<<<4608, 256, 0, stream>>>(Wq, wbuf);
  cast_f2b_k<<<1536, 256, 0, stream>>>(Wkv, wkvb);
  cast_f2b_k<<<1536, 256, 0, stream>>>(Wuv, wuvb);
  castT_f2b_k<<<dim3(16, 48), 256, 0, stream>>>(Wuk, wukT, 3072, 1024);

  // 1. absorbed_k = Wq @ Wuk            M=3072 N=1024 K=3072 -> bf16
  gemm_bf16<true, false><<<dim3(8, 24), 256, 0, stream>>>(
      wbuf, wukT, nullptr, akb, 3072, 1024, 3072);
  // Wout cast reuses wbuf after GEMM1 (serial stream)
  cast_f2b_k<<<4608, 256, 0, stream>>>(Wout, wbuf);
  // 2. c_pre = x @ Wkv^T                M=4096 N=1024 K=3072 -> fp32
  gemm_bf16<false, false><<<dim3(8, 32), 256, 0, stream>>>(
      xb, wkvb, nullptr, cpre, 4096, 1024, 3072);
  // 3. LayerNorm -> ckv (fp32 output) + ckvb (bf16)
  ln_k<<<4096, 256, 0, stream>>>(cpre, lng, lnb, ckv32, ckvb);
  // 4. k_full = ckv @ absorbed_k^T      M=4096 N=3072 K=1024 -> bf16
  gemm_bf16<true, false><<<dim3(24, 32), 256, 0, stream>>>(
      ckvb, akb, nullptr, kfullb, 4096, 3072, 1024);
  // 5. v_full = ckv @ Wuv^T             M=4096 N=3072 K=1024 -> bf16
  gemm_bf16<true, false><<<dim3(24, 32), 256, 0, stream>>>(
      ckvb, wuvb, nullptr, vfullb, 4096, 3072, 1024);
  // 6. per-batch transpose v_full -> vT [b][hd][t]
  transpose_b16_k<<<dim3(48, 32, 2), 256, 0, stream>>>(
      (const unsigned short*)vfullb, (unsigned short*)vTb);
  // 7. flash attention -> ctx (bf16, overwrites vfull)
  attn_mfma<<<1024, 256, 0, stream>>>(xb, kfullb, vTb, ctxb);
  // 8. out = ctx @ Wout^T + b_out       M=4096 N=3072 K=3072 -> fp32
  gemm_bf16<false, true><<<dim3(24, 32), 256, 0, stream>>>(
      ctxb, wbuf, bout, out, 4096, 3072, 3072);
}